// Round 1
// 403.686 us; speedup vs baseline: 1.0693x; 1.0693x over previous
//
#include <hip/hip_runtime.h>
#include <stdint.h>

#define M_DIM 8192
#define N_DIM 4096
#define K_DIM 4096

typedef int v4i __attribute__((ext_vector_type(4)));

// ---------------------------------------------------------------------------
// async global->LDS copy, 16 B per lane (wave-uniform LDS base + lane*16)
// ---------------------------------------------------------------------------
typedef __attribute__((address_space(1))) const void gas_void;
typedef __attribute__((address_space(3))) void las_void;

__device__ __forceinline__ void async_copy16(const uint8_t* g, uint8_t* l) {
    __builtin_amdgcn_global_load_lds((gas_void*)g, (las_void*)l, 16, 0, 0);
}

__device__ __forceinline__ int quant1(float x, float scale) {
    // Matches jnp.clip(jnp.round(x/scale), -127, 127): IEEE fp32 divide +
    // round-to-nearest-even (v_rndne), then clamp.
    float q = __builtin_rintf(x / scale);
    q = fminf(127.0f, fmaxf(-127.0f, q));
    return (int)q;
}

__device__ __forceinline__ uint32_t pack4(int q0, int q1, int q2, int q3) {
    return (uint32_t)(q0 & 255) | ((uint32_t)(q1 & 255) << 8) |
           ((uint32_t)(q2 & 255) << 16) | ((uint32_t)(q3 & 255) << 24);
}

// ---------------------------------------------------------------------------
// Kernel 1: per-row absmax + quantize lhs -> qlhs [M][K] int8 row-major
// ---------------------------------------------------------------------------
__global__ __launch_bounds__(256) void quant_lhs_kernel(
    const float* __restrict__ lhs, uint8_t* __restrict__ qlhs,
    float* __restrict__ lhs_scale) {
    const int row = blockIdx.x;
    const int tid = threadIdx.x;
    const float4* src = (const float4*)(lhs + (size_t)row * K_DIM);

    float4 v[4];
    float m = 0.0f;
#pragma unroll
    for (int i = 0; i < 4; ++i) {
        v[i] = src[tid + i * 256];
        m = fmaxf(m, fmaxf(fmaxf(fabsf(v[i].x), fabsf(v[i].y)),
                           fmaxf(fabsf(v[i].z), fabsf(v[i].w))));
    }
#pragma unroll
    for (int off = 32; off > 0; off >>= 1)
        m = fmaxf(m, __shfl_down(m, off, 64));

    __shared__ float wmax[4];
    if ((tid & 63) == 0) wmax[tid >> 6] = m;
    __syncthreads();
    const float mm = fmaxf(fmaxf(wmax[0], wmax[1]), fmaxf(wmax[2], wmax[3]));
    const float scale = (mm == 0.0f) ? 1.0f : mm / 127.0f;
    if (tid == 0) lhs_scale[row] = scale;

    uint32_t* dst = (uint32_t*)(qlhs + (size_t)row * K_DIM);
#pragma unroll
    for (int i = 0; i < 4; ++i) {
        dst[tid + i * 256] = pack4(quant1(v[i].x, scale), quant1(v[i].y, scale),
                                   quant1(v[i].z, scale), quant1(v[i].w, scale));
    }
}

// ---------------------------------------------------------------------------
// Kernel 2a: rhs column absmax. 32 rows per block (grid.y = 128);
// atomicMax on float bits (monotone for non-negative floats).
// ---------------------------------------------------------------------------
__global__ __launch_bounds__(256) void rhs_max_kernel(
    const float* __restrict__ rhs, uint32_t* __restrict__ maxbits) {
    const int c = blockIdx.x * 256 + threadIdx.x;
    const int r0 = blockIdx.y * 32;
    float m = 0.0f;
#pragma unroll
    for (int r = 0; r < 32; ++r)
        m = fmaxf(m, fabsf(rhs[(size_t)(r0 + r) * N_DIM + c]));
    atomicMax(&maxbits[c], __float_as_uint(m));
}

// ---------------------------------------------------------------------------
// Kernel 2b: quantize + transpose rhs -> qrhsT [N][K] int8 row-major.
// Scale computed inline from maxbits (same m/127.0f op as reference).
// Grid: (N/64, K/128) = (64, 32).
// ---------------------------------------------------------------------------
__global__ __launch_bounds__(256) void quant_rhs_t_kernel(
    const float* __restrict__ rhs, const uint32_t* __restrict__ maxbits,
    uint8_t* __restrict__ qrhsT) {
    __shared__ __align__(16) uint8_t tile[64 * 132];  // [n][k + 4B pad]
    const int nbase = blockIdx.x * 64;
    const int kbase = blockIdx.y * 128;
    const int tid = threadIdx.x;

    const int n0 = (tid & 15) * 4;
    float s[4];
#pragma unroll
    for (int j = 0; j < 4; ++j) {
        const float m = __uint_as_float(maxbits[nbase + n0 + j]);
        s[j] = (m == 0.0f) ? 1.0f : m / 127.0f;
    }

#pragma unroll
    for (int p = 0; p < 2; ++p) {
        const int k0 = (tid >> 4) * 4 + p * 64;
        int q[4][4];  // [i = k offset][j = n offset]
#pragma unroll
        for (int i = 0; i < 4; ++i) {
            const float4 v = *(const float4*)(
                rhs + (size_t)(kbase + k0 + i) * N_DIM + nbase + n0);
            q[i][0] = quant1(v.x, s[0]);
            q[i][1] = quant1(v.y, s[1]);
            q[i][2] = quant1(v.z, s[2]);
            q[i][3] = quant1(v.w, s[3]);
        }
#pragma unroll
        for (int j = 0; j < 4; ++j) {
            *(uint32_t*)(tile + (n0 + j) * 132 + k0) =
                pack4(q[0][j], q[1][j], q[2][j], q[3][j]);
        }
    }
    __syncthreads();

#pragma unroll
    for (int p = 0; p < 2; ++p) {
        const int c = tid + p * 256;
        const int n = c >> 3;
        const int g = c & 7;
        uint32_t d[4];
#pragma unroll
        for (int w = 0; w < 4; ++w)
            d[w] = *(const uint32_t*)(tile + n * 132 + g * 16 + w * 4);
        uint4 u;
        u.x = d[0]; u.y = d[1]; u.z = d[2]; u.w = d[3];
        *(uint4*)(qrhsT + (size_t)(nbase + n) * K_DIM + kbase + g * 16) = u;
    }
}

// ---------------------------------------------------------------------------
// Kernel 3: int8 GEMM, 256x256 tile, 8 waves (2Mx4N), deep-pipelined:
// 4-slot LDS ring (128 KB dynamic), compute K-tile t from slot t&3 while
// staging K-tile t+3 into slot (t+3)&3. Counted s_waitcnt vmcnt(8) once per
// K-tile (2 K-tiles of global_load_lds stay in flight across barriers --
// never drained to 0 in the main loop). Raw s_barrier (no compiler vmcnt
// drain), lgkmcnt(0)+sched_barrier before each MFMA cluster (rule #18),
// setprio(1) around MFMA (T5).
//
// LDS slot layout (32 KB): A [256 rows][64 B] at 0, B [256 rows][64 B] at
// 16384. 16B chunk g of row r stored at chunk g ^ ((r>>1)&3) -- the
// measured-zero-conflict swizzle; applied on the *global source* address for
// staging (global_load_lds writes linearly) and on the ds_read address.
// ---------------------------------------------------------------------------
__global__ __launch_bounds__(512, 2) void gemm_i8_kernel(
    const uint8_t* __restrict__ qlhs, const uint8_t* __restrict__ qrhsT,
    const float* __restrict__ lhs_scale, const uint32_t* __restrict__ maxbits,
    float* __restrict__ out) {
    extern __shared__ __align__(16) uint8_t smem[];  // 4 * 32768

    const int tid = threadIdx.x;
    const int wave = tid >> 6;
    const int lane = tid & 63;

    const int bm = blockIdx.y * 256;
    const int bn = blockIdx.x * 256;

    // ---- staging map: thread t covers 16B chunk (row = t>>2, chunk = t&3)
    // of a 128-row x 64B half; source chunk pre-swizzled so LDS is linear.
    const int srow = tid >> 2;
    const int gsrc = (((tid & 3) ^ ((tid >> 3) & 3)) << 4);
    const uint8_t* gA = qlhs + (size_t)(bm + srow) * K_DIM + gsrc;
    const uint8_t* gA2 = gA + (size_t)128 * K_DIM;
    const uint8_t* gB = qrhsT + (size_t)(bn + srow) * K_DIM + gsrc;
    const uint8_t* gB2 = gB + (size_t)128 * K_DIM;
    const uint32_t stO = (uint32_t)tid * 16u;

    // ---- fragment read map: row = w? + frag*16 + (lane&15), chunk = lane>>4,
    // swizzled chunk = (lane>>4) ^ ((lane>>1)&3) (row-bits 1..2 = lane-bits 1..2).
    const int wm = (wave >> 2) * 128;
    const int wn = (wave & 3) * 64;
    const uint32_t fg = (uint32_t)((((lane >> 4) ^ ((lane >> 1) & 3)) << 4));
    const uint32_t aoff = (uint32_t)((wm + (lane & 15)) * 64) + fg;
    const uint32_t boff = 16384u + (uint32_t)((wn + (lane & 15)) * 64) + fg;

    v4i acc[8][4] = {};

#define BARRIER() __builtin_amdgcn_s_barrier()
#define LGKM0()                                            \
    do {                                                   \
        asm volatile("s_waitcnt lgkmcnt(0)" ::: "memory"); \
        __builtin_amdgcn_sched_barrier(0);                 \
    } while (0)

    // ---- prologue: stage K-tiles 0,1,2 into slots 0,1,2 (12 issues/thread)
#pragma unroll
    for (int p = 0; p < 3; ++p) {
        uint8_t* sb = smem + (p << 15);
        async_copy16(gA, sb + stO);
        async_copy16(gA2, sb + 8192 + stO);
        async_copy16(gB, sb + 16384 + stO);
        async_copy16(gB2, sb + 24576 + stO);
        gA += 64; gA2 += 64; gB += 64; gB2 += 64;
    }
    asm volatile("s_waitcnt vmcnt(8)" ::: "memory");  // K-tile 0 landed
    BARRIER();

    // ---- main loop: 64 K-tiles of 64 bytes, 2 phases each
#pragma unroll 1
    for (int tt = 0; tt < 64; tt += 4) {
#pragma unroll
        for (int u = 0; u < 4; ++u) {
            const int t = tt + u;
            uint8_t* const Cb = smem + (u << 15);              // compute slot
            uint8_t* const Sb = smem + (((u + 3) & 3) << 15);  // stage slot

            v4i a[4], b[4];

            // ======== phase 1: mi 0..3 x ni 0..3 ========
#pragma unroll
            for (int i = 0; i < 4; ++i)
                a[i] = *(const v4i*)(Cb + aoff + i * 1024);
#pragma unroll
            for (int i = 0; i < 4; ++i)
                b[i] = *(const v4i*)(Cb + boff + i * 1024);
            async_copy16(gA, Sb + stO);          // A-lo of kt = t+3
            async_copy16(gA2, Sb + 8192 + stO);  // A-hi
            BARRIER();
            LGKM0();
            __builtin_amdgcn_s_setprio(1);
#pragma unroll
            for (int mi = 0; mi < 4; ++mi)
#pragma unroll
                for (int ni = 0; ni < 4; ++ni)
                    acc[mi][ni] = __builtin_amdgcn_mfma_i32_16x16x64_i8(
                        a[mi], b[ni], acc[mi][ni], 0, 0, 0);
            __builtin_amdgcn_s_setprio(0);
            BARRIER();

            // ======== phase 2: mi 4..7 x ni 0..3 (b[] reused) ========
#pragma unroll
            for (int i = 0; i < 4; ++i)
                a[i] = *(const v4i*)(Cb + aoff + (4 + i) * 1024);
            async_copy16(gB, Sb + 16384 + stO);   // B-lo of kt = t+3
            async_copy16(gB2, Sb + 24576 + stO);  // B-hi
            if (t < 60) {  // clamp at kt=63: t>=60 re-stages last tile
                gA += 64; gA2 += 64; gB += 64; gB2 += 64;
            }
            BARRIER();
            LGKM0();
            __builtin_amdgcn_s_setprio(1);
#pragma unroll
            for (int mi = 0; mi < 4; ++mi)
#pragma unroll
                for (int ni = 0; ni < 4; ++ni)
                    acc[4 + mi][ni] = __builtin_amdgcn_mfma_i32_16x16x64_i8(
                        a[mi], b[ni], acc[4 + mi][ni], 0, 0, 0);
            __builtin_amdgcn_s_setprio(0);
            // counted wait: allows kt=t+2, t+3 (8 loads) in flight; everything
            // <= kt=t+1 (needed next K-tile) is landed in EVERY wave before
            // the barrier releases.
            asm volatile("s_waitcnt vmcnt(8)" ::: "memory");
            BARRIER();
        }
    }
    // drain DMA before workgroup teardown / epilogue
    asm volatile("s_waitcnt vmcnt(0)" ::: "memory");

    // ---- epilogue: C/D layout col=lane&15, row=(lane>>4)*4+reg
    const int r0 = bm + wm + (lane >> 4) * 4;
    const int c0 = bn + wn + (lane & 15);
    float rsv[4];
#pragma unroll
    for (int ni = 0; ni < 4; ++ni) {
        const float m = __uint_as_float(maxbits[c0 + ni * 16]);
        rsv[ni] = (m == 0.0f) ? 1.0f : m / 127.0f;
    }
#pragma unroll
    for (int mi = 0; mi < 8; ++mi) {
        float ls[4];
#pragma unroll
        for (int r = 0; r < 4; ++r) ls[r] = lhs_scale[r0 + mi * 16 + r];
#pragma unroll
        for (int ni = 0; ni < 4; ++ni) {
            float* o = out + (size_t)(r0 + mi * 16) * N_DIM + c0 + ni * 16;
#pragma unroll
            for (int r = 0; r < 4; ++r)
                o[(size_t)r * N_DIM] = (float)acc[mi][ni][r] * ls[r] * rsv[ni];
        }
    }
#undef BARRIER
#undef LGKM0
}

// ---------------------------------------------------------------------------
// Workspace layout (bytes):
//   qlhs   [0, 33554432)
//   qrhsT  [33554432, 50331648)
//   lhs_scale (float[8192])   @ 50331648
//   (gap: old rhs_scale slot) @ 50364416
//   maxbits   (uint32[4096])  @ 50380800
// ---------------------------------------------------------------------------
extern "C" void kernel_launch(void* const* d_in, const int* in_sizes, int n_in,
                              void* d_out, int out_size, void* d_ws,
                              size_t ws_size, hipStream_t stream) {
    const float* lhs = (const float*)d_in[0];
    const float* rhs = (const float*)d_in[1];
    float* out = (float*)d_out;

    uint8_t* ws = (uint8_t*)d_ws;
    uint8_t* qlhs = ws;
    uint8_t* qrhsT = ws + 33554432u;
    float* lhs_scale = (float*)(ws + 50331648u);
    uint32_t* maxbits = (uint32_t*)(ws + 50380800u);

    static bool attr_set = false;
    if (!attr_set) {
        hipFuncSetAttribute((const void*)gemm_i8_kernel,
                            hipFuncAttributeMaxDynamicSharedMemorySize,
                            131072);
        attr_set = true;
    }

    hipMemsetAsync(maxbits, 0, N_DIM * sizeof(uint32_t), stream);

    quant_lhs_kernel<<<M_DIM, 256, 0, stream>>>(lhs, qlhs, lhs_scale);
    rhs_max_kernel<<<dim3(N_DIM / 256, 128), 256, 0, stream>>>(rhs, maxbits);
    quant_rhs_t_kernel<<<dim3(N_DIM / 64, K_DIM / 128), 256, 0, stream>>>(
        rhs, maxbits, qrhsT);
    gemm_i8_kernel<<<dim3(N_DIM / 256, M_DIM / 256), 512, 131072, stream>>>(
        qlhs, qrhsT, lhs_scale, maxbits, out);
}